// Round 1
// baseline (180.692 us; speedup 1.0000x reference)
//
#include <hip/hip_runtime.h>

#define P_TERMS 24

typedef _Float16 f16x8 __attribute__((ext_vector_type(8)));
typedef float f32x16 __attribute__((ext_vector_type(16)));

static __device__ __forceinline__ unsigned pack2(float a, float b) {
  unsigned short ua = __builtin_bit_cast(unsigned short, (_Float16)a);
  unsigned short ub = __builtin_bit_cast(unsigned short, (_Float16)b);
  return (unsigned)ua | ((unsigned)ub << 16);
}

static __device__ __forceinline__ unsigned pkadd(unsigned a, unsigned b) {
  unsigned d;
  asm("v_pk_add_f16 %0, %1, %2" : "=v"(d) : "v"(a), "v"(b));
  return d;
}

// ---------------- K1: c_p = A^p B (sequential, tiny), E[p][m] = C . c_p ----
__global__ __launch_bounds__(256) void s4_powers(
    const float* __restrict__ A, const float* __restrict__ B,
    const float* __restrict__ C, float* __restrict__ E) {
  __shared__ float cp[P_TERMS + 1][64];
  __shared__ float cur[64];
  const int tid = threadIdx.x;
  if (tid < 64) { cur[tid] = B[tid]; cp[0][tid] = B[tid]; }
  __syncthreads();
  const int n = tid >> 2, g = tid & 3;
  for (int p = 1; p <= P_TERMS; ++p) {
    float s = 0.f;
    const int j0 = g * 16;
#pragma unroll
    for (int j = 0; j < 16; ++j) s += A[n * 64 + j0 + j] * cur[j0 + j];
    s += __shfl_xor(s, 1);
    s += __shfl_xor(s, 2);
    __syncthreads();
    if (g == 0) { cur[n] = s; cp[p][n] = s; }
    __syncthreads();
  }
  const int m = tid;  // 0..255
#pragma unroll 1
  for (int p = 0; p <= P_TERMS; ++p) {
    float s = 0.f;
    for (int nn = 0; nn < 64; ++nn) s += C[m * 64 + nn] * cp[p][nn];
    E[p * 256 + m] = s;
  }
}

// ---------------- K2: W[k][m] = sum_p binom(k,p) dt^p E[p][m]; store f16 [m][k]
__global__ __launch_bounds__(512) void s4_wt(
    const float* __restrict__ E, const float* __restrict__ log_dt,
    _Float16* __restrict__ Wtb) {
  __shared__ float Em[P_TERMS + 1];
  const int m = blockIdx.x;
  const int k = threadIdx.x;  // 0..511
  if (k <= P_TERMS) Em[k] = E[k * 256 + m];
  __syncthreads();
  const float dt = __expf(log_dt[0]);
  float coef = 1.f, s = Em[0];
#pragma unroll 1
  for (int p = 1; p <= P_TERMS; ++p) {
    coef *= dt * (float)(k - p + 1) / (float)p;  // zero for p>k, stays zero
    s += coef * Em[p];
  }
  Wtb[m * 512 + k] = (_Float16)s;
}

// ---------------- K3: per-channel Y = dt * (G @ W) + 2 u D ---------------
// G[t,k] = u[t-k] + u[t+k] (guarded), built in-register from packed f16 quads.
__global__ __launch_bounds__(256) void s4_main(
    const float* __restrict__ x, const _Float16* __restrict__ Wtb,
    const float* __restrict__ Dvec, const float* __restrict__ log_dt,
    float* __restrict__ out) {
  __shared__ float us[512];
  __shared__ uint2 QF[1536];  // quads of guarded u: uf[i..i+3], uf[g]=u[g-512] on [512,1024)
  __shared__ uint2 QR[1536];  // quads of reversed:  ur[i..i+3], ur[j]=uf[1535-j]

  const int tid = threadIdx.x;
  const int bid = blockIdx.x;
  const int mt = bid & 1;
  const int tt = (bid >> 1) & 3;
  const int ch = bid >> 3;
  const int b = ch >> 8;
  const int d = ch & 255;

  for (int i = tid; i < 512; i += 256) us[i] = x[(b * 512 + i) * 256 + d];
  __syncthreads();

  auto ufv = [&](int g) -> float {
    return (g >= 512 && g < 1024) ? us[g - 512] : 0.f;
  };
  for (int i = tid; i < 1536; i += 256) {
    QF[i] = make_uint2(pack2(ufv(i), ufv(i + 1)), pack2(ufv(i + 2), ufv(i + 3)));
    QR[i] = make_uint2(pack2(ufv(1535 - i), ufv(1534 - i)),
                       pack2(ufv(1533 - i), ufv(1532 - i)));
  }
  __syncthreads();

  const int lane = tid & 63;
  const int wid = tid >> 6;
  const int wrow = wid >> 1, wcol = wid & 1;
  const int tbase = tt * 128 + wrow * 64;
  const int mbase = mt * 128 + wcol * 64;
  const int r = lane & 31;
  const int half8 = (lane >> 5) * 8;

  f32x16 acc[2][2];
#pragma unroll
  for (int i = 0; i < 2; ++i)
#pragma unroll
    for (int j = 0; j < 2; ++j)
#pragma unroll
      for (int e = 0; e < 16; ++e) acc[i][j][e] = 0.f;

  for (int kk = 0; kk < 512; kk += 16) {
    const int k0 = kk + half8;
    f16x8 bfrag[2];
#pragma unroll
    for (int mi = 0; mi < 2; ++mi)
      bfrag[mi] =
          *reinterpret_cast<const f16x8*>(&Wtb[(mbase + mi * 32 + r) * 512 + k0]);
#pragma unroll
    for (int ti = 0; ti < 2; ++ti) {
      const int t = tbase + ti * 32 + r;
      const int cf = 512 + t + k0;   // fwd: uf[cf + j], ascending
      const int ir = 1023 - t + k0;  // rev: ur[ir + j] = u[t-k0-j], ascending
      const uint2 q0 = QF[cf];
      const uint2 q1 = QF[cf + 4];
      const uint2 s0 = QR[ir];
      const uint2 s1 = QR[ir + 4];
      union { unsigned w[4]; f16x8 v; } af;
      af.w[0] = pkadd(q0.x, s0.x);
      af.w[1] = pkadd(q0.y, s0.y);
      af.w[2] = pkadd(q1.x, s1.x);
      af.w[3] = pkadd(q1.y, s1.y);
#pragma unroll
      for (int mi = 0; mi < 2; ++mi)
        acc[ti][mi] = __builtin_amdgcn_mfma_f32_32x32x16_f16(af.v, bfrag[mi],
                                                             acc[ti][mi], 0, 0, 0);
    }
  }

  const float dtv = __expf(log_dt[0]);
  const int halfq = (lane >> 5) * 4;
#pragma unroll
  for (int mi = 0; mi < 2; ++mi) {
    const int m = mbase + mi * 32 + r;
    const float Dm = Dvec[m];
#pragma unroll
    for (int ti = 0; ti < 2; ++ti) {
#pragma unroll
      for (int reg = 0; reg < 16; ++reg) {
        const int trow = tbase + ti * 32 + (reg & 3) + 8 * (reg >> 2) + halfq;
        const float uv = us[trow];
        out[(((size_t)b * 512 + trow) * 256 + d) * 256 + m] =
            dtv * acc[ti][mi][reg] + 2.f * uv * Dm;
      }
    }
  }
}

extern "C" void kernel_launch(void* const* d_in, const int* in_sizes, int n_in,
                              void* d_out, int out_size, void* d_ws, size_t ws_size,
                              hipStream_t stream) {
  (void)in_sizes; (void)n_in; (void)out_size; (void)ws_size;
  const float* x = (const float*)d_in[0];
  const float* A = (const float*)d_in[1];
  const float* B = (const float*)d_in[2];
  const float* C = (const float*)d_in[3];
  const float* D = (const float*)d_in[4];
  const float* log_dt = (const float*)d_in[5];
  float* out = (float*)d_out;

  float* E = (float*)d_ws;                              // 25*256*4 = 25.6 KB
  _Float16* Wtb = (_Float16*)((char*)d_ws + 32768);     // 256*512*2 = 256 KB

  s4_powers<<<1, 256, 0, stream>>>(A, B, C, E);
  s4_wt<<<256, 512, 0, stream>>>(E, log_dt, Wtb);
  s4_main<<<4096, 256, 0, stream>>>(x, Wtb, D, log_dt, out);
}